// Round 19
// baseline (176.931 us; speedup 1.0000x reference)
//
#include <hip/hip_runtime.h>
#include <hip/hip_fp16.h>

#define T1 512
#define NB 32      // batches
#define NP 96      // 3 pairs * 32 batches
#define DHEAD 64

#define RSLOTS 128                 // LDS ring slots (1 KB column each) = 131072 B, pow2
#define RBYTES (RSLOTS * 1024)
#define PFD 32                     // producer prefetch distance (columns ahead)

typedef __attribute__((ext_vector_type(8))) short bf16x8;
typedef __attribute__((ext_vector_type(4))) float f32x4;
typedef __attribute__((ext_vector_type(4))) unsigned int u32x4;

// ---------------- kernel 1: fused normalize + MFMA bf16 GEMM -> W f16 ----------------
// Each block normalizes its own 128 A-rows and 128 B-rows (f32 -> bf16, RNE) into LDS
// ([128][72] ushort: 144B rows, 16B-aligned for b128 fragment reads), then runs the
// proven MFMA tile + LDS-staged coalesced W store (round 16). Kills the separate
// k_normalize kernel and the xb/yb global round-trip. Redundant normalization across
// blocks sharing rows is benign (identical values, no global writes).
__global__ __launch_bounds__(256) void k_gemm_w(const float* __restrict__ x,
                                                const float* __restrict__ y,
                                                __half* __restrict__ W) {
  __shared__ __attribute__((aligned(16))) __half blk[128][132];   // 33792 B
  __shared__ __attribute__((aligned(16))) ushort xnL[128][72];    // 18432 B
  __shared__ __attribute__((aligned(16))) ushort ynL[128][72];    // 18432 B
  int pb = blockIdx.z;            // 0..95
  int p  = pb >> 5;               // 0:xy 1:xx 2:yy
  int b  = pb & 31;
  int i0b = blockIdx.x * 128, j0b = blockIdx.y * 128;
  const float* Asrc = ((p == 2) ? y : x) + (size_t)b * T1 * DHEAD + (size_t)i0b * DHEAD;
  const float* Bsrc = ((p == 1) ? x : y) + (size_t)b * T1 * DHEAD + (size_t)j0b * DHEAD;

  int wid = threadIdx.x >> 6, lane = threadIdx.x & 63;

  // phase 0: normalize (one wave per row, lane per element; 32 rows per wave per side)
  #pragma unroll 1
  for (int r = wid; r < 128; r += 4) {
    float v = Asrc[(size_t)r * DHEAD + lane];
    float s = v * v;
    #pragma unroll
    for (int off = 32; off > 0; off >>= 1) s += __shfl_xor(s, off);
    float o = v * (1.0f / fmaxf(sqrtf(s), 1e-12f));
    unsigned u = __float_as_uint(o);
    xnL[r][lane] = (ushort)((u + 0x7fffu + ((u >> 16) & 1u)) >> 16);   // RNE bf16
  }
  #pragma unroll 1
  for (int r = wid; r < 128; r += 4) {
    float v = Bsrc[(size_t)r * DHEAD + lane];
    float s = v * v;
    #pragma unroll
    for (int off = 32; off > 0; off >>= 1) s += __shfl_xor(s, off);
    float o = v * (1.0f / fmaxf(sqrtf(s), 1e-12f));
    unsigned u = __float_as_uint(o);
    ynL[r][lane] = (ushort)((u + 0x7fffu + ((u >> 16) & 1u)) >> 16);
  }
  __syncthreads();

  // phase 1: MFMA (fragments from LDS; layout identical to the proven global path)
  int wm = wid >> 1, wn = wid & 1;
  int lr = lane & 15, kg = lane >> 4;

  f32x4 acc[4][4];
  #pragma unroll
  for (int ic = 0; ic < 4; ++ic)
    #pragma unroll
    for (int jc = 0; jc < 4; ++jc) acc[ic][jc] = (f32x4){0.f, 0.f, 0.f, 0.f};

  #pragma unroll
  for (int kk = 0; kk < 2; ++kk) {
    int ko = kk * 32 + kg * 8;
    bf16x8 af[4], bf[4];
    #pragma unroll
    for (int ic = 0; ic < 4; ++ic)
      af[ic] = *reinterpret_cast<const bf16x8*>(&xnL[wm * 64 + ic * 16 + lr][ko]);
    #pragma unroll
    for (int jc = 0; jc < 4; ++jc)
      bf[jc] = *reinterpret_cast<const bf16x8*>(&ynL[wn * 64 + jc * 16 + lr][ko]);
    #pragma unroll
    for (int ic = 0; ic < 4; ++ic)
      #pragma unroll
      for (int jc = 0; jc < 4; ++jc)
        acc[ic][jc] = __builtin_amdgcn_mfma_f32_16x16x32_bf16(af[ic], bf[jc], acc[ic][jc], 0, 0, 0);
  }

  // epilogue pass 1: exp + pack, stage into LDS at [local j][local i]
  const float NLOG2E = -1.44269504088896340736f;
  #pragma unroll
  for (int ic = 0; ic < 4; ++ic) {
    int il = wm * 64 + ic * 16 + (kg << 2);
    #pragma unroll
    for (int jc = 0; jc < 4; ++jc) {
      int jl = wn * 64 + jc * 16 + lr;
      union { __half h[4]; uint2 u; } pk;
      #pragma unroll
      for (int r = 0; r < 4; ++r) {
        float d = 1.0f - acc[ic][jc][r];
        pk.h[r] = __float2half(exp2f(NLOG2E * d));
      }
      *reinterpret_cast<uint2*>(&blk[jl][il]) = pk.u;
    }
  }
  __syncthreads();

  // epilogue pass 2: coalesced store — 16 lanes x 16B = 256 contiguous B per W row
  __half* Wp = W + (size_t)pb * (T1 * T1);
  int tr = threadIdx.x >> 4;
  int tc = threadIdx.x & 15;
  #pragma unroll
  for (int q = 0; q < 8; ++q) {
    int j = q * 16 + tr;
    u32x4 v = *reinterpret_cast<const u32x4*>(&blk[j][tc << 3]);
    *reinterpret_cast<u32x4*>(Wp + (size_t)(j0b + j) * T1 + i0b + (tc << 3)) = v;
  }
}

// ---------------- kernel 2: soft-DTW (r17 exact, proven 54.3us) + atomic combine ------
// Lane l owns DP rows 8l+1..8l+8; col j = t - lane at step t; 36 groups of 16 steps.
// DP math: chained FMA scan, exact pow2 renorm every 16 cols (KK15), group-hoisted base
// scales, DPP wave_shr lane exchange. W feed: 128-slot LDS column ring, SALU-uniform
// producer addressing, PFD=32, counted vmcnt(16) at group top & mid. Guards: tb<64 +
// final group. Readout: lane63 last active t=574 (KK14, even -> Vb) -> Vb[7].
// NEW: fused combine — lane63 atomicAdds coeff*sdtw into out[b] (coeff: p0=+1,
// p1/p2=-0.5); d_out zeroed by memsetAsync each launch. Atomic order varies only in
// final-ulp rounding (<< 5.68 threshold).
__global__ __launch_bounds__(64, 1) void k_dtw(const __half* __restrict__ W,
                                               float* __restrict__ out) {
  __shared__ __attribute__((aligned(16))) char ring[RBYTES];
  const int prob = blockIdx.x;
  const __half* Wp = W + (size_t)prob * (T1 * T1);
  const int lane = threadIdx.x;

  float Va[8], Vb[8];
  #pragma unroll
  for (int r = 0; r < 8; ++r) { Va[r] = 0.f; Vb[r] = 0.f; }
  float B2 = 0.f, B2p = 0.f;
  const float dgSeed = (lane == 0) ? 1.0f : 0.0f;

  auto dppshr = [](float v) -> float {   // lane l <- lane l-1; lane 0 <- 0 (VALU only)
    return __int_as_float(__builtin_amdgcn_update_dpp(
        0, __float_as_int(v), 0x138 /*wave_shr:1*/, 0xF, 0xF, true));
  };

#define SCALEBITS(dexp) __uint_as_float( \
    (unsigned)(127 + (int)fminf(fmaxf((dexp), -120.f), 120.f)) << 23)

  // producer: uniform column byte offset (SALU) + constant per-lane byte offset
  const char* gW = (const char*)Wp;
  const unsigned laneOff = (unsigned)(lane << 4);   // 16 B/lane slice
  size_t colOff = (size_t)PFD << 10;                // uniform, next col to issue
  unsigned lslot = (PFD << 10) & (RBYTES - 1);      // uniform LDS slot byte offset

  // prologue: issue cols 0..31
  #pragma unroll
  for (int c = 0; c < PFD; ++c) {
    __builtin_amdgcn_global_load_lds(
        (const __attribute__((address_space(1))) void*)(gW + ((size_t)c << 10) + laneOff),
        (__attribute__((address_space(3))) void*)(ring + ((unsigned)(c << 10))), 16, 0, 0);
  }
  asm volatile("s_waitcnt vmcnt(24)" ::: "memory");   // cols 0..7 landed

  u32x4 d0, d1, d2, d3, d4, d5, d6, d7;
  unsigned va0, va1, va2, va3, va4, va5, va6, va7;
#define RS_INIT(K) do { \
    d##K = *reinterpret_cast<const u32x4*>( \
        ring + ((((unsigned)(K - lane) & 127u) << 10) | (unsigned)(lane << 4))); \
    va##K = ((((unsigned)(8 + K - lane) & 127u) << 10) | (unsigned)(lane << 4)); \
  } while (0)
  RS_INIT(0); RS_INIT(1); RS_INIT(2); RS_INIT(3);
  RS_INIT(4); RS_INIT(5); RS_INIT(6); RS_INIT(7);
#undef RS_INIT

#define DTW_STEP(KK, BUF, VIN, VOUT, SDG, SEEDK, GUARD, RENORM) do {          \
    const int t_ = tb + (KK);                                                 \
    float nbUp_ = dppshr(VIN[7]);            /* neighbor end of t-1 */        \
    float nbDg_ = dppshr(VOUT[7]);           /* neighbor end of t-2 */        \
    float up_ = nbUp_ * sUp;                                                  \
    float dg_ = nbDg_ * (SDG);                                                \
    if (SEEDK) dg_ = dgSeed;                                                  \
    union { u32x4 u; __half h[8]; } cv_; cv_.u = d##BUF;                      \
    d##BUF = *reinterpret_cast<const u32x4*>(ring + va##BUF);  /* col t_+8 */ \
    va##BUF = (va##BUF + 8192u) & (RBYTES - 1);                               \
    __builtin_amdgcn_global_load_lds(                          /* col issue */\
        (const __attribute__((address_space(1))) void*)(gW + colOff + laneOff),\
        (__attribute__((address_space(3))) void*)(ring + lslot), 16, 0, 0);   \
    lslot = (lslot + 1024u) & (RBYTES - 1);                                   \
    colOff += ((t_ + PFD) < (T1 - 1)) ? 1024 : 0;  /* uniform; freezes @511 */\
    float wv_[8];                                                             \
    _Pragma("unroll")                                                         \
    for (int r = 0; r < 8; ++r) wv_[r] = __half2float(cv_.h[r]);              \
    bool act_ = true;                                                         \
    if (GUARD) { int j_ = t_ - lane; act_ = ((unsigned)j_ < (unsigned)T1); }  \
    if (act_) {                                                               \
      float c_ = fmaf(wv_[0], up_, wv_[0] * (dg_ + VIN[0]));                  \
      VOUT[0] = c_;                                                           \
      _Pragma("unroll")                                                       \
      for (int r = 1; r < 8; ++r) {                                           \
        c_ = fmaf(wv_[r], c_, wv_[r] * (VIN[r-1] + VIN[r]));                  \
        VOUT[r] = c_;                                                         \
      }                                                                       \
      if (RENORM) {                          /* exact pow2 renorm, per 16 */  \
        float m_ = fmaxf(fmaxf(fmaxf(VOUT[0],VOUT[1]),fmaxf(VOUT[2],VOUT[3])),\
                         fmaxf(fmaxf(VOUT[4],VOUT[5]),fmaxf(VOUT[6],VOUT[7])));\
        int e_ = (int)((__float_as_uint(m_) >> 23) & 0xFF) - 127;             \
        e_ = e_ < -126 ? -126 : (e_ > 126 ? 126 : e_);                        \
        float sc_ = __uint_as_float((unsigned)(127 - e_) << 23);              \
        _Pragma("unroll")                                                     \
        for (int r = 0; r < 8; ++r) VOUT[r] *= sc_;                           \
        B2p = B2; B2 -= (float)e_;                                            \
      }                                                                       \
    }                                                                         \
  } while (0)

#define DTW_GROUP(GUARD, SEED) do {                                           \
    asm volatile("s_waitcnt vmcnt(16)" ::: "memory");  /* cols <= tb+15 */    \
    float nbBn_ = dppshr(B2);                /* neighbor base, post-renorm */ \
    float nbBo_ = dppshr(B2p);               /* neighbor base, pre-renorm  */ \
    float sUp  = SCALEBITS(B2 - nbBn_);                                       \
    float sDg0 = SCALEBITS(B2 - nbBo_);                                       \
    DTW_STEP(0,  0, Va, Vb, sDg0, SEED,  GUARD, false);                       \
    DTW_STEP(1,  1, Vb, Va, sUp,  false, GUARD, false);                       \
    DTW_STEP(2,  2, Va, Vb, sUp,  false, GUARD, false);                       \
    DTW_STEP(3,  3, Vb, Va, sUp,  false, GUARD, false);                       \
    DTW_STEP(4,  4, Va, Vb, sUp,  false, GUARD, false);                       \
    DTW_STEP(5,  5, Vb, Va, sUp,  false, GUARD, false);                       \
    DTW_STEP(6,  6, Va, Vb, sUp,  false, GUARD, false);                       \
    DTW_STEP(7,  7, Vb, Va, sUp,  false, GUARD, false);                       \
    asm volatile("s_waitcnt vmcnt(16)" ::: "memory");  /* cols <= tb+23 */    \
    DTW_STEP(8,  0, Va, Vb, sUp,  false, GUARD, false);                       \
    DTW_STEP(9,  1, Vb, Va, sUp,  false, GUARD, false);                       \
    DTW_STEP(10, 2, Va, Vb, sUp,  false, GUARD, false);                       \
    DTW_STEP(11, 3, Vb, Va, sUp,  false, GUARD, false);                       \
    DTW_STEP(12, 4, Va, Vb, sUp,  false, GUARD, false);                       \
    DTW_STEP(13, 5, Vb, Va, sUp,  false, GUARD, false);                       \
    DTW_STEP(14, 6, Va, Vb, sUp,  false, GUARD, false);                       \
    DTW_STEP(15, 7, Vb, Va, sUp,  false, GUARD, true);                        \
  } while (0)

  // 36 groups of 16 steps = 576. Guarded: tb=0(seed),16,32,48 (head, t<64) and
  // tb=560 (protects lane63's final value at t=575). Middle 31 groups unguarded.
  { const int tb = 0; DTW_GROUP(true, true); }
  #pragma unroll 1
  for (int tb = 16; tb < 64; tb += 16)   DTW_GROUP(true,  false);
  #pragma unroll 1
  for (int tb = 64; tb < 560; tb += 16)  DTW_GROUP(false, false);
  { const int tb = 560; DTW_GROUP(true, false); }

  if (lane == 63) {
    // lane63's last ACTIVE step t=574 (KK14, even -> wrote Vb): col 511 = R[512][512].
    float val = (B2 - log2f(Vb[7])) * 0.69314718055994530942f;
    float coeff = (prob < 32) ? 1.0f : -0.5f;
    atomicAdd(out + (prob & 31), coeff * val);
  }
#undef DTW_STEP
#undef DTW_GROUP
#undef SCALEBITS
}

extern "C" void kernel_launch(void* const* d_in, const int* in_sizes, int n_in,
                              void* d_out, int out_size, void* d_ws, size_t ws_size,
                              hipStream_t stream) {
  const float* x = (const float*)d_in[0];
  const float* y = (const float*)d_in[1];
  float* out = (float*)d_out;

  const size_t need = (size_t)3 * NB * T1 * T1 * sizeof(__half);   // 50.33 MB (W only)
  if (ws_size < need) {
    hipMemsetAsync(d_out, 0xFF, (size_t)out_size * sizeof(float), stream);
    return;
  }
  __half* W = (__half*)d_ws;

  hipMemsetAsync(d_out, 0, (size_t)out_size * sizeof(float), stream);  // atomic target
  hipLaunchKernelGGL(k_gemm_w, dim3(4, 4, 96), dim3(256), 0, stream, x, y, W);
  hipLaunchKernelGGL(k_dtw, dim3(NP), dim3(64), 0, stream, W, out);
}

// Round 20
// 88.183 us; speedup vs baseline: 2.0064x; 2.0064x over previous
//
#include <hip/hip_runtime.h>
#include <hip/hip_fp16.h>

#define T1 512
#define NB 32      // batches
#define NP 96      // 3 pairs * 32 batches
#define DHEAD 64

#define RSLOTS 128                 // LDS ring slots (1 KB column each) = 131072 B, pow2
#define RBYTES (RSLOTS * 1024)
#define PFD 32                     // producer prefetch distance (columns ahead)

typedef __attribute__((ext_vector_type(8))) short bf16x8;
typedef __attribute__((ext_vector_type(4))) float f32x4;
typedef __attribute__((ext_vector_type(4))) unsigned int u32x4;

// ---------------- kernel 1: row-normalize x,y -> bf16 (round-17 exact) ----------------
__global__ __launch_bounds__(256) void k_normalize(const float* __restrict__ x,
                                                   const float* __restrict__ y,
                                                   ushort* __restrict__ xb,
                                                   ushort* __restrict__ yb) {
  int wid  = threadIdx.x >> 6;
  int lane = threadIdx.x & 63;
  int row  = blockIdx.x * 4 + wid;          // 0 .. 32767
  const float* src; ushort* dst;
  if (row < NB * T1) { src = x + (size_t)row * DHEAD;            dst = xb + (size_t)row * DHEAD; }
  else { int r2 = row - NB * T1; src = y + (size_t)r2 * DHEAD;   dst = yb + (size_t)r2 * DHEAD; }
  float v = src[lane];
  float s = v * v;
  #pragma unroll
  for (int off = 32; off > 0; off >>= 1) s += __shfl_xor(s, off);
  float rn = 1.0f / fmaxf(sqrtf(s), 1e-12f);
  float o = v * rn;
  unsigned u = __float_as_uint(o);
  unsigned r = (u + 0x7fffu + ((u >> 16) & 1u)) >> 16;   // RNE to bf16
  dst[lane] = (ushort)r;
}

// ---------------- kernel 2: MFMA bf16 GEMM -> W[p][b][j][i] = exp(-(1-dot)) f16 -------
// Round-17 exact: fragments direct from global (xb/yb L2-resident), LDS-staged
// coalesced W store (full 64B-sector utilization).
__global__ __launch_bounds__(256) void k_gemm_w(const ushort* __restrict__ xb,
                                                const ushort* __restrict__ yb,
                                                __half* __restrict__ W) {
  __shared__ __attribute__((aligned(16))) __half blk[128][132];   // 33792 B
  int pb = blockIdx.z;            // 0..95
  int p  = pb >> 5;               // 0:xy 1:xx 2:yy
  int b  = pb & 31;
  const ushort* A  = ((p == 2) ? yb : xb) + (size_t)b * T1 * DHEAD;  // i-side (M)
  const ushort* Bm = ((p == 1) ? xb : yb) + (size_t)b * T1 * DHEAD;  // j-side (N)

  int wid = threadIdx.x >> 6, lane = threadIdx.x & 63;
  int wm = wid >> 1, wn = wid & 1;
  int i0b = blockIdx.x * 128, j0b = blockIdx.y * 128;
  int i0 = i0b + wm * 64;
  int j0 = j0b + wn * 64;
  int lr = lane & 15, kg = lane >> 4;

  f32x4 acc[4][4];
  #pragma unroll
  for (int ic = 0; ic < 4; ++ic)
    #pragma unroll
    for (int jc = 0; jc < 4; ++jc) acc[ic][jc] = (f32x4){0.f, 0.f, 0.f, 0.f};

  #pragma unroll
  for (int kk = 0; kk < 2; ++kk) {
    int ko = kk * 32 + kg * 8;
    bf16x8 af[4], bf[4];
    #pragma unroll
    for (int ic = 0; ic < 4; ++ic)
      af[ic] = *reinterpret_cast<const bf16x8*>(A + (size_t)(i0 + ic * 16 + lr) * DHEAD + ko);
    #pragma unroll
    for (int jc = 0; jc < 4; ++jc)
      bf[jc] = *reinterpret_cast<const bf16x8*>(Bm + (size_t)(j0 + jc * 16 + lr) * DHEAD + ko);
    #pragma unroll
    for (int ic = 0; ic < 4; ++ic)
      #pragma unroll
      for (int jc = 0; jc < 4; ++jc)
        acc[ic][jc] = __builtin_amdgcn_mfma_f32_16x16x32_bf16(af[ic], bf[jc], acc[ic][jc], 0, 0, 0);
  }

  // epilogue pass 1: exp + pack, stage into LDS at [local j][local i]
  const float NLOG2E = -1.44269504088896340736f;
  #pragma unroll
  for (int ic = 0; ic < 4; ++ic) {
    int il = wm * 64 + ic * 16 + (kg << 2);
    #pragma unroll
    for (int jc = 0; jc < 4; ++jc) {
      int jl = wn * 64 + jc * 16 + lr;
      union { __half h[4]; uint2 u; } pk;
      #pragma unroll
      for (int r = 0; r < 4; ++r) {
        float d = 1.0f - acc[ic][jc][r];
        pk.h[r] = __float2half(exp2f(NLOG2E * d));
      }
      *reinterpret_cast<uint2*>(&blk[jl][il]) = pk.u;
    }
  }
  __syncthreads();

  // epilogue pass 2: coalesced store — 16 lanes x 16B = 256 contiguous B per W row
  __half* Wp = W + (size_t)pb * (T1 * T1);
  int tr = threadIdx.x >> 4;
  int tc = threadIdx.x & 15;
  #pragma unroll
  for (int q = 0; q < 8; ++q) {
    int j = q * 16 + tr;
    u32x4 v = *reinterpret_cast<const u32x4*>(&blk[j][tc << 3]);
    *reinterpret_cast<u32x4*>(Wp + (size_t)(j0b + j) * T1 + i0b + (tc << 3)) = v;
  }
}

// ---------------- kernel 3: soft-DTW (r17 exact, 54.3us proven) + atomic combine ------
// Lane l owns DP rows 8l+1..8l+8; col j = t - lane at step t; 36 groups of 16 steps.
// Chained FMA scan, exact pow2 renorm every 16 cols (KK15), group-hoisted base scales,
// DPP wave_shr exchange. W feed: 128-slot LDS column ring, SALU-uniform producer
// addressing, PFD=32, counted vmcnt(16) at group top & mid. Guards: tb<64 + final
// group. Readout: lane63 last active t=574 (KK14, even -> Vb) -> Vb[7]; fused combine
// via atomicAdd (coeff p0=+1, p1/p2=-0.5); out zeroed by memsetAsync each launch.
__global__ __launch_bounds__(64, 1) void k_dtw(const __half* __restrict__ W,
                                               float* __restrict__ out) {
  __shared__ __attribute__((aligned(16))) char ring[RBYTES];
  const int prob = blockIdx.x;
  const __half* Wp = W + (size_t)prob * (T1 * T1);
  const int lane = threadIdx.x;

  float Va[8], Vb[8];
  #pragma unroll
  for (int r = 0; r < 8; ++r) { Va[r] = 0.f; Vb[r] = 0.f; }
  float B2 = 0.f, B2p = 0.f;
  const float dgSeed = (lane == 0) ? 1.0f : 0.0f;

  auto dppshr = [](float v) -> float {   // lane l <- lane l-1; lane 0 <- 0 (VALU only)
    return __int_as_float(__builtin_amdgcn_update_dpp(
        0, __float_as_int(v), 0x138 /*wave_shr:1*/, 0xF, 0xF, true));
  };

#define SCALEBITS(dexp) __uint_as_float( \
    (unsigned)(127 + (int)fminf(fmaxf((dexp), -120.f), 120.f)) << 23)

  // producer: uniform column byte offset (SALU) + constant per-lane byte offset
  const char* gW = (const char*)Wp;
  const unsigned laneOff = (unsigned)(lane << 4);   // 16 B/lane slice
  size_t colOff = (size_t)PFD << 10;                // uniform, next col to issue
  unsigned lslot = (PFD << 10) & (RBYTES - 1);      // uniform LDS slot byte offset

  // prologue: issue cols 0..31
  #pragma unroll
  for (int c = 0; c < PFD; ++c) {
    __builtin_amdgcn_global_load_lds(
        (const __attribute__((address_space(1))) void*)(gW + ((size_t)c << 10) + laneOff),
        (__attribute__((address_space(3))) void*)(ring + ((unsigned)(c << 10))), 16, 0, 0);
  }
  asm volatile("s_waitcnt vmcnt(24)" ::: "memory");   // cols 0..7 landed

  u32x4 d0, d1, d2, d3, d4, d5, d6, d7;
  unsigned va0, va1, va2, va3, va4, va5, va6, va7;
#define RS_INIT(K) do { \
    d##K = *reinterpret_cast<const u32x4*>( \
        ring + ((((unsigned)(K - lane) & 127u) << 10) | (unsigned)(lane << 4))); \
    va##K = ((((unsigned)(8 + K - lane) & 127u) << 10) | (unsigned)(lane << 4)); \
  } while (0)
  RS_INIT(0); RS_INIT(1); RS_INIT(2); RS_INIT(3);
  RS_INIT(4); RS_INIT(5); RS_INIT(6); RS_INIT(7);
#undef RS_INIT

#define DTW_STEP(KK, BUF, VIN, VOUT, SDG, SEEDK, GUARD, RENORM) do {          \
    const int t_ = tb + (KK);                                                 \
    float nbUp_ = dppshr(VIN[7]);            /* neighbor end of t-1 */        \
    float nbDg_ = dppshr(VOUT[7]);           /* neighbor end of t-2 */        \
    float up_ = nbUp_ * sUp;                                                  \
    float dg_ = nbDg_ * (SDG);                                                \
    if (SEEDK) dg_ = dgSeed;                                                  \
    union { u32x4 u; __half h[8]; } cv_; cv_.u = d##BUF;                      \
    d##BUF = *reinterpret_cast<const u32x4*>(ring + va##BUF);  /* col t_+8 */ \
    va##BUF = (va##BUF + 8192u) & (RBYTES - 1);                               \
    __builtin_amdgcn_global_load_lds(                          /* col issue */\
        (const __attribute__((address_space(1))) void*)(gW + colOff + laneOff),\
        (__attribute__((address_space(3))) void*)(ring + lslot), 16, 0, 0);   \
    lslot = (lslot + 1024u) & (RBYTES - 1);                                   \
    colOff += ((t_ + PFD) < (T1 - 1)) ? 1024 : 0;  /* uniform; freezes @511 */\
    float wv_[8];                                                             \
    _Pragma("unroll")                                                         \
    for (int r = 0; r < 8; ++r) wv_[r] = __half2float(cv_.h[r]);              \
    bool act_ = true;                                                         \
    if (GUARD) { int j_ = t_ - lane; act_ = ((unsigned)j_ < (unsigned)T1); }  \
    if (act_) {                                                               \
      float c_ = fmaf(wv_[0], up_, wv_[0] * (dg_ + VIN[0]));                  \
      VOUT[0] = c_;                                                           \
      _Pragma("unroll")                                                       \
      for (int r = 1; r < 8; ++r) {                                           \
        c_ = fmaf(wv_[r], c_, wv_[r] * (VIN[r-1] + VIN[r]));                  \
        VOUT[r] = c_;                                                         \
      }                                                                       \
      if (RENORM) {                          /* exact pow2 renorm, per 16 */  \
        float m_ = fmaxf(fmaxf(fmaxf(VOUT[0],VOUT[1]),fmaxf(VOUT[2],VOUT[3])),\
                         fmaxf(fmaxf(VOUT[4],VOUT[5]),fmaxf(VOUT[6],VOUT[7])));\
        int e_ = (int)((__float_as_uint(m_) >> 23) & 0xFF) - 127;             \
        e_ = e_ < -126 ? -126 : (e_ > 126 ? 126 : e_);                        \
        float sc_ = __uint_as_float((unsigned)(127 - e_) << 23);              \
        _Pragma("unroll")                                                     \
        for (int r = 0; r < 8; ++r) VOUT[r] *= sc_;                           \
        B2p = B2; B2 -= (float)e_;                                            \
      }                                                                       \
    }                                                                         \
  } while (0)

#define DTW_GROUP(GUARD, SEED) do {                                           \
    asm volatile("s_waitcnt vmcnt(16)" ::: "memory");  /* cols <= tb+15 */    \
    float nbBn_ = dppshr(B2);                /* neighbor base, post-renorm */ \
    float nbBo_ = dppshr(B2p);               /* neighbor base, pre-renorm  */ \
    float sUp  = SCALEBITS(B2 - nbBn_);                                       \
    float sDg0 = SCALEBITS(B2 - nbBo_);                                       \
    DTW_STEP(0,  0, Va, Vb, sDg0, SEED,  GUARD, false);                       \
    DTW_STEP(1,  1, Vb, Va, sUp,  false, GUARD, false);                       \
    DTW_STEP(2,  2, Va, Vb, sUp,  false, GUARD, false);                       \
    DTW_STEP(3,  3, Vb, Va, sUp,  false, GUARD, false);                       \
    DTW_STEP(4,  4, Va, Vb, sUp,  false, GUARD, false);                       \
    DTW_STEP(5,  5, Vb, Va, sUp,  false, GUARD, false);                       \
    DTW_STEP(6,  6, Va, Vb, sUp,  false, GUARD, false);                       \
    DTW_STEP(7,  7, Vb, Va, sUp,  false, GUARD, false);                       \
    asm volatile("s_waitcnt vmcnt(16)" ::: "memory");  /* cols <= tb+23 */    \
    DTW_STEP(8,  0, Va, Vb, sUp,  false, GUARD, false);                       \
    DTW_STEP(9,  1, Vb, Va, sUp,  false, GUARD, false);                       \
    DTW_STEP(10, 2, Va, Vb, sUp,  false, GUARD, false);                       \
    DTW_STEP(11, 3, Vb, Va, sUp,  false, GUARD, false);                       \
    DTW_STEP(12, 4, Va, Vb, sUp,  false, GUARD, false);                       \
    DTW_STEP(13, 5, Vb, Va, sUp,  false, GUARD, false);                       \
    DTW_STEP(14, 6, Va, Vb, sUp,  false, GUARD, false);                       \
    DTW_STEP(15, 7, Vb, Va, sUp,  false, GUARD, true);                        \
  } while (0)

  // 36 groups of 16 steps = 576. Guarded: tb=0(seed),16,32,48 (head, t<64) and
  // tb=560 (protects lane63's final value at t=575). Middle 31 groups unguarded.
  { const int tb = 0; DTW_GROUP(true, true); }
  #pragma unroll 1
  for (int tb = 16; tb < 64; tb += 16)   DTW_GROUP(true,  false);
  #pragma unroll 1
  for (int tb = 64; tb < 560; tb += 16)  DTW_GROUP(false, false);
  { const int tb = 560; DTW_GROUP(true, false); }

  if (lane == 63) {
    // lane63's last ACTIVE step t=574 (KK14, even -> wrote Vb): col 511 = R[512][512].
    float val = (B2 - log2f(Vb[7])) * 0.69314718055994530942f;
    float coeff = (prob < 32) ? 1.0f : -0.5f;
    atomicAdd(out + (prob & 31), coeff * val);
  }
#undef DTW_STEP
#undef DTW_GROUP
#undef SCALEBITS
}

extern "C" void kernel_launch(void* const* d_in, const int* in_sizes, int n_in,
                              void* d_out, int out_size, void* d_ws, size_t ws_size,
                              hipStream_t stream) {
  const float* x = (const float*)d_in[0];
  const float* y = (const float*)d_in[1];
  float* out = (float*)d_out;

  const size_t xb_off  = 0;
  const size_t yb_off  = (size_t)NB * T1 * DHEAD * sizeof(ushort);           // 2 MB
  const size_t W_off   = 2 * yb_off;                                          // 4 MB
  const size_t need    = W_off + (size_t)3 * NB * T1 * T1 * sizeof(__half);   // +50.33 MB

  if (ws_size < need) {
    hipMemsetAsync(d_out, 0xFF, (size_t)out_size * sizeof(float), stream);
    return;
  }

  ushort* xb = (ushort*)((char*)d_ws + xb_off);
  ushort* yb = (ushort*)((char*)d_ws + yb_off);
  __half* W  = (__half*)((char*)d_ws + W_off);

  hipMemsetAsync(d_out, 0, (size_t)out_size * sizeof(float), stream);  // atomic target
  hipLaunchKernelGGL(k_normalize, dim3(8192), dim3(256), 0, stream, x, y, xb, yb);
  hipLaunchKernelGGL(k_gemm_w, dim3(4, 4, 96), dim3(256), 0, stream, xb, yb, W);
  hipLaunchKernelGGL(k_dtw, dim3(NP), dim3(64), 0, stream, W, out);
}

// Round 21
// 82.668 us; speedup vs baseline: 2.1403x; 1.0667x over previous
//
#include <hip/hip_runtime.h>
#include <hip/hip_fp16.h>

#define T1 512
#define NB 32      // batches
#define NP 96      // 3 pairs * 32 batches
#define DHEAD 64

#define RSLOTS 128                 // LDS ring slots (1 KB column each) = 131072 B, pow2
#define RBYTES (RSLOTS * 1024)
#define PFD 32                     // producer prefetch distance (columns ahead)

typedef __attribute__((ext_vector_type(8))) short bf16x8;
typedef __attribute__((ext_vector_type(4))) float f32x4;
typedef __attribute__((ext_vector_type(4))) unsigned int u32x4;

// ---------------- kernel 1: row-normalize x,y -> bf16 (+ zero the atomic target) ------
// r17-exact body; block 0 additionally zeroes out[0..31]. Stream ordering guarantees
// the zeros precede k_dtw's atomics; removes the separate memset dispatch.
__global__ __launch_bounds__(256) void k_normalize(const float* __restrict__ x,
                                                   const float* __restrict__ y,
                                                   ushort* __restrict__ xb,
                                                   ushort* __restrict__ yb,
                                                   float* __restrict__ out) {
  if (blockIdx.x == 0 && threadIdx.x < NB) out[threadIdx.x] = 0.0f;
  int wid  = threadIdx.x >> 6;
  int lane = threadIdx.x & 63;
  int row  = blockIdx.x * 4 + wid;          // 0 .. 32767
  const float* src; ushort* dst;
  if (row < NB * T1) { src = x + (size_t)row * DHEAD;            dst = xb + (size_t)row * DHEAD; }
  else { int r2 = row - NB * T1; src = y + (size_t)r2 * DHEAD;   dst = yb + (size_t)r2 * DHEAD; }
  float v = src[lane];
  float s = v * v;
  #pragma unroll
  for (int off = 32; off > 0; off >>= 1) s += __shfl_xor(s, off);
  float rn = 1.0f / fmaxf(sqrtf(s), 1e-12f);
  float o = v * rn;
  unsigned u = __float_as_uint(o);
  unsigned r = (u + 0x7fffu + ((u >> 16) & 1u)) >> 16;   // RNE to bf16
  dst[lane] = (ushort)r;
}

// ---------------- kernel 2: MFMA bf16 GEMM -> W[p][b][j][i] = exp(-(1-dot)) f16 -------
// Round-17 exact: fragments direct from global (xb/yb L2-resident), LDS-staged
// coalesced W store (full 64B-sector utilization).
__global__ __launch_bounds__(256) void k_gemm_w(const ushort* __restrict__ xb,
                                                const ushort* __restrict__ yb,
                                                __half* __restrict__ W) {
  __shared__ __attribute__((aligned(16))) __half blk[128][132];   // 33792 B
  int pb = blockIdx.z;            // 0..95
  int p  = pb >> 5;               // 0:xy 1:xx 2:yy
  int b  = pb & 31;
  const ushort* A  = ((p == 2) ? yb : xb) + (size_t)b * T1 * DHEAD;  // i-side (M)
  const ushort* Bm = ((p == 1) ? xb : yb) + (size_t)b * T1 * DHEAD;  // j-side (N)

  int wid = threadIdx.x >> 6, lane = threadIdx.x & 63;
  int wm = wid >> 1, wn = wid & 1;
  int i0b = blockIdx.x * 128, j0b = blockIdx.y * 128;
  int i0 = i0b + wm * 64;
  int j0 = j0b + wn * 64;
  int lr = lane & 15, kg = lane >> 4;

  f32x4 acc[4][4];
  #pragma unroll
  for (int ic = 0; ic < 4; ++ic)
    #pragma unroll
    for (int jc = 0; jc < 4; ++jc) acc[ic][jc] = (f32x4){0.f, 0.f, 0.f, 0.f};

  #pragma unroll
  for (int kk = 0; kk < 2; ++kk) {
    int ko = kk * 32 + kg * 8;
    bf16x8 af[4], bf[4];
    #pragma unroll
    for (int ic = 0; ic < 4; ++ic)
      af[ic] = *reinterpret_cast<const bf16x8*>(A + (size_t)(i0 + ic * 16 + lr) * DHEAD + ko);
    #pragma unroll
    for (int jc = 0; jc < 4; ++jc)
      bf[jc] = *reinterpret_cast<const bf16x8*>(Bm + (size_t)(j0 + jc * 16 + lr) * DHEAD + ko);
    #pragma unroll
    for (int ic = 0; ic < 4; ++ic)
      #pragma unroll
      for (int jc = 0; jc < 4; ++jc)
        acc[ic][jc] = __builtin_amdgcn_mfma_f32_16x16x32_bf16(af[ic], bf[jc], acc[ic][jc], 0, 0, 0);
  }

  // epilogue pass 1: exp + pack, stage into LDS at [local j][local i]
  const float NLOG2E = -1.44269504088896340736f;
  #pragma unroll
  for (int ic = 0; ic < 4; ++ic) {
    int il = wm * 64 + ic * 16 + (kg << 2);
    #pragma unroll
    for (int jc = 0; jc < 4; ++jc) {
      int jl = wn * 64 + jc * 16 + lr;
      union { __half h[4]; uint2 u; } pk;
      #pragma unroll
      for (int r = 0; r < 4; ++r) {
        float d = 1.0f - acc[ic][jc][r];
        pk.h[r] = __float2half(exp2f(NLOG2E * d));
      }
      *reinterpret_cast<uint2*>(&blk[jl][il]) = pk.u;
    }
  }
  __syncthreads();

  // epilogue pass 2: coalesced store — 16 lanes x 16B = 256 contiguous B per W row
  __half* Wp = W + (size_t)pb * (T1 * T1);
  int tr = threadIdx.x >> 4;
  int tc = threadIdx.x & 15;
  #pragma unroll
  for (int q = 0; q < 8; ++q) {
    int j = q * 16 + tr;
    u32x4 v = *reinterpret_cast<const u32x4*>(&blk[j][tc << 3]);
    *reinterpret_cast<u32x4*>(Wp + (size_t)(j0b + j) * T1 + i0b + (tc << 3)) = v;
  }
}

// ---------------- kernel 3: soft-DTW (r17 exact, 54.3us proven) + atomic combine ------
// Lane l owns DP rows 8l+1..8l+8; col j = t - lane at step t; 36 groups of 16 steps.
// Chained FMA scan, exact pow2 renorm every 16 cols (KK15), group-hoisted base scales,
// DPP wave_shr exchange. W feed: 128-slot LDS column ring, SALU-uniform producer
// addressing, PFD=32, counted vmcnt(16) at group top & mid. Guards: tb<64 + final
// group. Readout: lane63 last active t=574 (KK14, even -> Vb) -> Vb[7]; fused combine
// via atomicAdd (coeff p0=+1, p1/p2=-0.5); out zeroed by k_normalize block 0.
__global__ __launch_bounds__(64, 1) void k_dtw(const __half* __restrict__ W,
                                               float* __restrict__ out) {
  __shared__ __attribute__((aligned(16))) char ring[RBYTES];
  const int prob = blockIdx.x;
  const __half* Wp = W + (size_t)prob * (T1 * T1);
  const int lane = threadIdx.x;

  float Va[8], Vb[8];
  #pragma unroll
  for (int r = 0; r < 8; ++r) { Va[r] = 0.f; Vb[r] = 0.f; }
  float B2 = 0.f, B2p = 0.f;
  const float dgSeed = (lane == 0) ? 1.0f : 0.0f;

  auto dppshr = [](float v) -> float {   // lane l <- lane l-1; lane 0 <- 0 (VALU only)
    return __int_as_float(__builtin_amdgcn_update_dpp(
        0, __float_as_int(v), 0x138 /*wave_shr:1*/, 0xF, 0xF, true));
  };

#define SCALEBITS(dexp) __uint_as_float( \
    (unsigned)(127 + (int)fminf(fmaxf((dexp), -120.f), 120.f)) << 23)

  // producer: uniform column byte offset (SALU) + constant per-lane byte offset
  const char* gW = (const char*)Wp;
  const unsigned laneOff = (unsigned)(lane << 4);   // 16 B/lane slice
  size_t colOff = (size_t)PFD << 10;                // uniform, next col to issue
  unsigned lslot = (PFD << 10) & (RBYTES - 1);      // uniform LDS slot byte offset

  // prologue: issue cols 0..31
  #pragma unroll
  for (int c = 0; c < PFD; ++c) {
    __builtin_amdgcn_global_load_lds(
        (const __attribute__((address_space(1))) void*)(gW + ((size_t)c << 10) + laneOff),
        (__attribute__((address_space(3))) void*)(ring + ((unsigned)(c << 10))), 16, 0, 0);
  }
  asm volatile("s_waitcnt vmcnt(24)" ::: "memory");   // cols 0..7 landed

  u32x4 d0, d1, d2, d3, d4, d5, d6, d7;
  unsigned va0, va1, va2, va3, va4, va5, va6, va7;
#define RS_INIT(K) do { \
    d##K = *reinterpret_cast<const u32x4*>( \
        ring + ((((unsigned)(K - lane) & 127u) << 10) | (unsigned)(lane << 4))); \
    va##K = ((((unsigned)(8 + K - lane) & 127u) << 10) | (unsigned)(lane << 4)); \
  } while (0)
  RS_INIT(0); RS_INIT(1); RS_INIT(2); RS_INIT(3);
  RS_INIT(4); RS_INIT(5); RS_INIT(6); RS_INIT(7);
#undef RS_INIT

#define DTW_STEP(KK, BUF, VIN, VOUT, SDG, SEEDK, GUARD, RENORM) do {          \
    const int t_ = tb + (KK);                                                 \
    float nbUp_ = dppshr(VIN[7]);            /* neighbor end of t-1 */        \
    float nbDg_ = dppshr(VOUT[7]);           /* neighbor end of t-2 */        \
    float up_ = nbUp_ * sUp;                                                  \
    float dg_ = nbDg_ * (SDG);                                                \
    if (SEEDK) dg_ = dgSeed;                                                  \
    union { u32x4 u; __half h[8]; } cv_; cv_.u = d##BUF;                      \
    d##BUF = *reinterpret_cast<const u32x4*>(ring + va##BUF);  /* col t_+8 */ \
    va##BUF = (va##BUF + 8192u) & (RBYTES - 1);                               \
    __builtin_amdgcn_global_load_lds(                          /* col issue */\
        (const __attribute__((address_space(1))) void*)(gW + colOff + laneOff),\
        (__attribute__((address_space(3))) void*)(ring + lslot), 16, 0, 0);   \
    lslot = (lslot + 1024u) & (RBYTES - 1);                                   \
    colOff += ((t_ + PFD) < (T1 - 1)) ? 1024 : 0;  /* uniform; freezes @511 */\
    float wv_[8];                                                             \
    _Pragma("unroll")                                                         \
    for (int r = 0; r < 8; ++r) wv_[r] = __half2float(cv_.h[r]);              \
    bool act_ = true;                                                         \
    if (GUARD) { int j_ = t_ - lane; act_ = ((unsigned)j_ < (unsigned)T1); }  \
    if (act_) {                                                               \
      float c_ = fmaf(wv_[0], up_, wv_[0] * (dg_ + VIN[0]));                  \
      VOUT[0] = c_;                                                           \
      _Pragma("unroll")                                                       \
      for (int r = 1; r < 8; ++r) {                                           \
        c_ = fmaf(wv_[r], c_, wv_[r] * (VIN[r-1] + VIN[r]));                  \
        VOUT[r] = c_;                                                         \
      }                                                                       \
      if (RENORM) {                          /* exact pow2 renorm, per 16 */  \
        float m_ = fmaxf(fmaxf(fmaxf(VOUT[0],VOUT[1]),fmaxf(VOUT[2],VOUT[3])),\
                         fmaxf(fmaxf(VOUT[4],VOUT[5]),fmaxf(VOUT[6],VOUT[7])));\
        int e_ = (int)((__float_as_uint(m_) >> 23) & 0xFF) - 127;             \
        e_ = e_ < -126 ? -126 : (e_ > 126 ? 126 : e_);                        \
        float sc_ = __uint_as_float((unsigned)(127 - e_) << 23);              \
        _Pragma("unroll")                                                     \
        for (int r = 0; r < 8; ++r) VOUT[r] *= sc_;                           \
        B2p = B2; B2 -= (float)e_;                                            \
      }                                                                       \
    }                                                                         \
  } while (0)

#define DTW_GROUP(GUARD, SEED) do {                                           \
    asm volatile("s_waitcnt vmcnt(16)" ::: "memory");  /* cols <= tb+15 */    \
    float nbBn_ = dppshr(B2);                /* neighbor base, post-renorm */ \
    float nbBo_ = dppshr(B2p);               /* neighbor base, pre-renorm  */ \
    float sUp  = SCALEBITS(B2 - nbBn_);                                       \
    float sDg0 = SCALEBITS(B2 - nbBo_);                                       \
    DTW_STEP(0,  0, Va, Vb, sDg0, SEED,  GUARD, false);                       \
    DTW_STEP(1,  1, Vb, Va, sUp,  false, GUARD, false);                       \
    DTW_STEP(2,  2, Va, Vb, sUp,  false, GUARD, false);                       \
    DTW_STEP(3,  3, Vb, Va, sUp,  false, GUARD, false);                       \
    DTW_STEP(4,  4, Va, Vb, sUp,  false, GUARD, false);                       \
    DTW_STEP(5,  5, Vb, Va, sUp,  false, GUARD, false);                       \
    DTW_STEP(6,  6, Va, Vb, sUp,  false, GUARD, false);                       \
    DTW_STEP(7,  7, Vb, Va, sUp,  false, GUARD, false);                       \
    asm volatile("s_waitcnt vmcnt(16)" ::: "memory");  /* cols <= tb+23 */    \
    DTW_STEP(8,  0, Va, Vb, sUp,  false, GUARD, false);                       \
    DTW_STEP(9,  1, Vb, Va, sUp,  false, GUARD, false);                       \
    DTW_STEP(10, 2, Va, Vb, sUp,  false, GUARD, false);                       \
    DTW_STEP(11, 3, Vb, Va, sUp,  false, GUARD, false);                       \
    DTW_STEP(12, 4, Va, Vb, sUp,  false, GUARD, false);                       \
    DTW_STEP(13, 5, Vb, Va, sUp,  false, GUARD, false);                       \
    DTW_STEP(14, 6, Va, Vb, sUp,  false, GUARD, false);                       \
    DTW_STEP(15, 7, Vb, Va, sUp,  false, GUARD, true);                        \
  } while (0)

  // 36 groups of 16 steps = 576. Guarded: tb=0(seed),16,32,48 (head, t<64) and
  // tb=560 (protects lane63's final value at t=575). Middle 31 groups unguarded.
  { const int tb = 0; DTW_GROUP(true, true); }
  #pragma unroll 1
  for (int tb = 16; tb < 64; tb += 16)   DTW_GROUP(true,  false);
  #pragma unroll 1
  for (int tb = 64; tb < 560; tb += 16)  DTW_GROUP(false, false);
  { const int tb = 560; DTW_GROUP(true, false); }

  if (lane == 63) {
    // lane63's last ACTIVE step t=574 (KK14, even -> wrote Vb): col 511 = R[512][512].
    float val = (B2 - log2f(Vb[7])) * 0.69314718055994530942f;
    float coeff = (prob < 32) ? 1.0f : -0.5f;
    atomicAdd(out + (prob & 31), coeff * val);
  }
#undef DTW_STEP
#undef DTW_GROUP
#undef SCALEBITS
}

extern "C" void kernel_launch(void* const* d_in, const int* in_sizes, int n_in,
                              void* d_out, int out_size, void* d_ws, size_t ws_size,
                              hipStream_t stream) {
  const float* x = (const float*)d_in[0];
  const float* y = (const float*)d_in[1];
  float* out = (float*)d_out;

  const size_t xb_off  = 0;
  const size_t yb_off  = (size_t)NB * T1 * DHEAD * sizeof(ushort);           // 2 MB
  const size_t W_off   = 2 * yb_off;                                          // 4 MB
  const size_t need    = W_off + (size_t)3 * NB * T1 * T1 * sizeof(__half);   // +50.33 MB

  if (ws_size < need) {
    hipMemsetAsync(d_out, 0xFF, (size_t)out_size * sizeof(float), stream);
    return;
  }

  ushort* xb = (ushort*)((char*)d_ws + xb_off);
  ushort* yb = (ushort*)((char*)d_ws + yb_off);
  __half* W  = (__half*)((char*)d_ws + W_off);

  hipLaunchKernelGGL(k_normalize, dim3(8192), dim3(256), 0, stream, x, y, xb, yb, out);
  hipLaunchKernelGGL(k_gemm_w, dim3(4, 4, 96), dim3(256), 0, stream, xb, yb, W);
  hipLaunchKernelGGL(k_dtw, dim3(NP), dim3(64), 0, stream, W, out);
}